// Round 2
// baseline (1391.931 us; speedup 1.0000x reference)
//
#include <hip/hip_runtime.h>
#include <cstdint>
#include <cstddef>

// ---------------------------------------------------------------------------
// ClassifierLSTMDeltas on gfx950 — bf16 MFMA pipeline, round 5.
// Shapes: B=4096 T=31 C=768 BD=128 AUG=384 HID=256 H=64 O=12
// Round-5: k2+k3+k3b fused into k2_mega. Each block owns 4 batches (124 rows)
// and runs: GEMM1(K=768,N=384) -> stencil/GELU/LN -> xaug in LDS ->
// GEMM2(K=384,N=256, A from LDS) -> GELU+time-mean -> xlstm in LDS ->
// GEMM3(K=256,N=512 in 2 passes) -> +bias -> PRE (HBM, coalesced).
// Eliminates XAUG (195MB w+r) and XLSTM (65MB w + 260MB r) HBM traffic and
// two stall-bound kernel launches. 512 thr / 8 waves, wave-tile 64x96 for
// GEMM1 (MFMA-bound: LDS 1250cyc/kt < MFMA 1862cyc/kt), ~156KB LDS,
// 2-phase dbuf staging with pre-swizzled global_load_lds (round-4 pattern).
// PRE relocated to old XAUG region (mega-kernel reads XS while writing PRE).
// k0/k1/k1b/k4/k5 unchanged.
// ---------------------------------------------------------------------------

typedef short s8v __attribute__((ext_vector_type(8)));   // 8 bf16 (4 VGPR) MFMA frag
typedef float f4v __attribute__((ext_vector_type(4)));   // MFMA acc

#if defined(__has_builtin)
#if __has_builtin(__builtin_amdgcn_global_load_lds)
#define HAVE_GLL 1
#endif
#endif
#ifndef HAVE_GLL
#define HAVE_GLL 0
#endif

__device__ __forceinline__ unsigned short f2bf(float f) {
  union { float f; unsigned int u; } v; v.f = f;
  unsigned int u = v.u;
  return (unsigned short)((u + 0x7fffu + ((u >> 16) & 1u)) >> 16);  // RNE
}
__device__ __forceinline__ float bf2f(unsigned short h) {
  union { unsigned int u; float f; } v; v.u = ((unsigned int)h) << 16;
  return v.f;
}
__device__ __forceinline__ float fsig(float x) {
  return __fdividef(1.f, 1.f + __expf(-x));
}
__device__ __forceinline__ float ftanh(float x) {
  return 1.f - __fdividef(2.f, 1.f + __expf(2.f * x));
}
__device__ __forceinline__ float fgelu(float x) {          // exact gelu (erf)
  return 0.5f * x * (1.f + erff(x * 0.70710678118654752f));
}

// async 16B global->LDS. ldsU is the WAVE-UNIFORM destination base; HW lands
// lane i at ldsU + i*16 (per cdna_hip_programming §5 caveat). g is per-lane.
__device__ __forceinline__ void ld_lds16(const unsigned short* g,
                                         unsigned short* ldsU, int lane) {
#if HAVE_GLL
  __builtin_amdgcn_global_load_lds(
      (__attribute__((address_space(1))) void*)(uintptr_t)(const void*)g,
      (__attribute__((address_space(3))) void*)(unsigned int)(uintptr_t)(void*)ldsU,
      16, 0, 0);
#else
  *(uint4*)(ldsU + lane * 8) = *(const uint4*)g;
#endif
}
__device__ __forceinline__ void wait_vm0() {
#if HAVE_GLL
  __builtin_amdgcn_s_waitcnt(0x0F70);   // vmcnt(0), lgkm/exp unconstrained
#endif
}

// ---- workspace layout (bytes) ---------------------------------------------
#define OFF_W1T   0u            // [384][768] bf16   (cls|delta|acc transposed)
#define OFF_W2T   589824u       // [256][384] bf16   (lin0 transposed)
#define OFF_WIHT  786432u       // [512][256] bf16   (wih_f rows 0-255, wih_r 256-511)
#define OFF_WHHT  1048576u      // [2][256][64] bf16 (whh transposed per dir)
#define OFF_XS    1114112u      // [126976][768] bf16 x_smooth
#define OFF_XW    196149248u    // [4096][768] f32 window mean
#define OFF_LL    208732160u    // [4096][12] f32 linear_logits
#define OFF_WIN   208928768u    // [4096][11][128] bf16 lstm window
#define OFF_PRE   220463104u    // [126976][512] bf16 pre (own region: k2_mega
                                // reads XS while writing PRE -> no alias)

// ===========================================================================
// k0: transpose + bf16-convert all GEMM weights into [N][K] layout
// ===========================================================================
__global__ __launch_bounds__(256) void k0_prep(
    const float* __restrict__ cls_w, const float* __restrict__ delta_w,
    const float* __restrict__ acc_w, const float* __restrict__ lin0_w,
    const float* __restrict__ wih_f, const float* __restrict__ wih_r,
    const float* __restrict__ whh_f, const float* __restrict__ whh_r,
    unsigned short* __restrict__ ws) {
  int i = blockIdx.x * 256 + threadIdx.x;        // 557056 total elements
  if (i < 294912) {                              // W1t[n][k], n in [0,384)
    int n = i / 768, k = i - n * 768;
    int seg = n >> 7, nn = n & 127;
    const float* w = seg == 0 ? cls_w : (seg == 1 ? delta_w : acc_w);
    ws[i] = f2bf(w[k * 128 + nn]);
  } else if (i < 393216) {                       // W2t[n][k], n in [0,256), k in [0,384)
    int j = i - 294912;
    int n = j / 384, k = j - n * 384;
    ws[i] = f2bf(lin0_w[k * 256 + n]);
  } else if (i < 524288) {                       // Wiht[n][k], n in [0,512), k in [0,256)
    int j = i - 393216;
    int n = j >> 8, k = j & 255;
    ws[i] = f2bf(n < 256 ? wih_f[k * 256 + n] : wih_r[k * 256 + (n - 256)]);
  } else if (i < 557056) {                       // Whht[d][n][k]
    int j = i - 524288;
    int d = j >> 14, rem = j & 16383;
    int n = rem >> 6, k = rem & 63;
    const float* w = d ? whh_r : whh_f;
    ws[i] = f2bf(w[k * 256 + n]);
  }
}

// ===========================================================================
// k1: EMA scan over T per (b,c); write bf16 x_smooth + fp32 window mean
// ===========================================================================
__global__ __launch_bounds__(256) void k1_ema(
    const float* __restrict__ x, unsigned short* __restrict__ xs,
    float* __restrict__ xw) {
  int gid = blockIdx.x * 256 + threadIdx.x;      // b*768 + c
  int b = gid / 768;
  int c = gid - b * 768;
  size_t base = (size_t)b * 31 * 768 + c;
  float s = x[base];
  xs[base] = f2bf(s);
  float wsum = 0.f;
#pragma unroll
  for (int t = 1; t < 31; ++t) {
    float xv = x[base + t * 768];
    s = s + 0.3f * (xv - s);
    xs[base + t * 768] = f2bf(s);
    if (t >= 10 && t <= 20) wsum += s;
  }
  xw[gid] = wsum * (1.f / 11.f);
}

// ===========================================================================
// k1b: linear_logits = xw_mean @ lin1_w + lin1_b   (one wave per batch row)
// ===========================================================================
__global__ __launch_bounds__(64) void k1b_linlog(
    const float* __restrict__ xw, const float* __restrict__ lin1_w,
    const float* __restrict__ lin1_b, float* __restrict__ ll) {
  int b = blockIdx.x;
  int lane = threadIdx.x;
  float p[12];
#pragma unroll
  for (int o = 0; o < 12; ++o) p[o] = 0.f;
  for (int k = lane; k < 768; k += 64) {
    float xv = xw[b * 768 + k];
    const float* w = lin1_w + k * 12;
#pragma unroll
    for (int o = 0; o < 12; ++o) p[o] += xv * w[o];
  }
#pragma unroll
  for (int o = 0; o < 12; ++o) {
    float v = p[o];
#pragma unroll
    for (int s = 1; s < 64; s <<= 1) v += __shfl_xor(v, s, 64);
    p[o] = v;
  }
  if (lane == 0) {
#pragma unroll
    for (int o = 0; o < 12; ++o) ll[b * 12 + o] = p[o] + lin1_b[o];
  }
}

// time-stencil (reflect-pad derivative streams) + bias + exact GELU.
// sP is [31][388] f32, one batch, seg-padded cols (seg*130 + c).
__device__ __forceinline__ float stencil_gelu3(const float* sP, const float* sBias,
                                               int seg, int t, int c) {
  const float* p = sP + t * 388 + seg * 130 + c;
  float v;
  if (seg == 0) {
    v = p[0];
  } else if (seg == 1) {                          // delta: s_t - s_{t-1}; t=0: s0-s1
    v = (t == 0) ? (p[0] - p[388]) : (p[0] - p[-388]);
  } else {                                        // acc: s_t-2s_{t-1}+s_{t-2}; edges reflect
    if (t == 0)      v = p[0] - 2.f * p[388] + p[776];
    else if (t == 1) v = 2.f * (p[0] - p[-388]);
    else             v = p[0] - 2.f * p[-388] + p[-776];
  }
  return fgelu(v + sBias[seg * 128 + c]);
}

// ===========================================================================
// k2_mega: per block = 124 rows (4 batches x 31 t).
//   Phase 1: P1 = xs @ W1t^T  (128x384 tile, 8 waves 2Mx4N, wave 64x96)
//   Ep 1   : stencil+GELU+LN -> xaug bf16 [124][392] in LDS
//   Phase 2: P2 = xaug @ W2t^T (N=256, BK=32, A direct from LDS)
//   Ep 2   : GELU+bias, per-batch time-mean subtract -> xlstm [124][260] LDS
//   Phase 3: P3 = xlstm @ Wiht^T (N=512 in 2 passes of 256, BK=64)
//   Ep 3   : +bias -> bf16 -> PRE (coalesced 16B stores via LDS repack)
// LDS aliasing map (region: [live span]):
//   stg1 dbuf   @0      128KB [phase1]      xaug @0      97.2KB [ep1..gemm2]
//   xlstm       @0      64.5KB [ep2..gemm3] stg3 dbuf @65536 64KB [gemm3]
//   sPb         @65536  16.4KB [ep3]        sP1  @98304  48.1KB [ep1]
//   stg2 dbuf   @98304  32KB  [gemm2]       sP2  @98304  32.2KB [ep2]
//   consts      @146688 9.5KB [whole kernel]
// ===========================================================================
__global__ __launch_bounds__(512, 2) void k2_mega(
    const unsigned short* __restrict__ xs, const unsigned short* __restrict__ W1t,
    const unsigned short* __restrict__ W2t, const unsigned short* __restrict__ Wiht,
    const float* __restrict__ cls_b, const float* __restrict__ delta_b,
    const float* __restrict__ acc_b,
    const float* __restrict__ g0, const float* __restrict__ be0,
    const float* __restrict__ g1, const float* __restrict__ be1,
    const float* __restrict__ g2, const float* __restrict__ be2,
    const float* __restrict__ lin0_b, const float* __restrict__ b_f,
    const float* __restrict__ b_r, unsigned short* __restrict__ pre) {
  __shared__ __align__(16) char smem[156160];
  unsigned short* stg1  = (unsigned short*)smem;             // 2 x 64KB
  unsigned short* xaug  = (unsigned short*)smem;             // [124][392]
  unsigned short* xlstm = (unsigned short*)smem;             // [124][260]
  unsigned short* stg3  = (unsigned short*)(smem + 65536);   // 2 x 32KB
  unsigned short* sPb   = (unsigned short*)(smem + 65536);   // [31][264] bf16
  float*          sP1   = (float*)(smem + 98304);            // [31][388]
  unsigned short* stg2  = (unsigned short*)(smem + 98304);   // 2 x 16KB
  float*          sP2   = (float*)(smem + 98304);            // [31][260]
  float* sBias = (float*)(smem + 146688);                    // [384]
  float* sG    = sBias + 384;                                // [384]
  float* sLb   = sG + 384;                                   // [384]
  float* sMu   = sLb + 384;                                  // [93]
  float* sRs   = sMu + 93;                                   // [93]
  float* sL0b  = sRs + 93;                                   // [256]
  float* sB3   = sL0b + 256;                                 // [512]
  float* sCM   = sB3 + 512;                                  // [256]

  const int tid  = threadIdx.x;
  const int lane = tid & 63;
  const int wv   = tid >> 6;            // 0..7
  const int l15  = lane & 15;
  const int quad = lane >> 4;
  const int wm   = wv >> 2;             // 0..1  M half
  const int wn   = wv & 3;              // 0..3  N slot
  const int rowBase = blockIdx.x * 124;

  // ---- constants (used only after many barriers; no sync needed here) -----
  if (tid < 384) {
    int seg = tid >> 7, c = tid & 127;
    sBias[tid] = seg == 0 ? cls_b[c] : (seg == 1 ? delta_b[c] : acc_b[c]);
    sG[tid]    = seg == 0 ? g0[c]    : (seg == 1 ? g1[c]    : g2[c]);
    sLb[tid]   = seg == 0 ? be0[c]   : (seg == 1 ? be1[c]   : be2[c]);
  }
  if (tid < 256) sL0b[tid] = lin0_b[tid];
  sB3[tid] = tid < 256 ? b_f[tid] : b_r[tid - 256];

  // ==================== PHASE 1: GEMM1 (K=768, BK=64) ======================
  // combined staged tile: [A rows 0..127 | B rows 0..383] x 64 shorts;
  // 64 slices of 1KB (8 rows), wave wv owns slices 8wv..8wv+7.
  const int subrow  = lane >> 3;                 // 0..7 row within slice
  const int schunk8 = ((lane & 7) ^ subrow) * 8; // pre-swizzled source chunk
  const int swz     = (l15 & 7) << 3;            // read-side XOR (shorts)
  const unsigned short* src1[8];
#pragma unroll
  for (int j = 0; j < 8; ++j) {
    int row = (wv * 8 + j) * 8 + subrow;         // 0..511
    src1[j] = (row < 128)
        ? xs + (size_t)(rowBase + (row < 124 ? row : 123)) * 768 + schunk8
        : W1t + (size_t)(row - 128) * 768 + schunk8;
  }

  f4v acc1[4][6];
#pragma unroll
  for (int mt = 0; mt < 4; ++mt)
#pragma unroll
    for (int nt = 0; nt < 6; ++nt) acc1[mt][nt] = (f4v){0.f, 0.f, 0.f, 0.f};

#pragma unroll
  for (int j = 0; j < 8; ++j) ld_lds16(src1[j], stg1 + (wv * 8 + j) * 512, lane);
  wait_vm0();
  __syncthreads();

  for (int kt = 0; kt < 12; ++kt) {
    unsigned short* bc = stg1 + (kt & 1) * 32768;
    unsigned short* bn = stg1 + ((kt & 1) ^ 1) * 32768;
    if (kt < 11) {
#pragma unroll
      for (int j = 0; j < 8; ++j)
        ld_lds16(src1[j] + (kt + 1) * 64, bn + (wv * 8 + j) * 512, lane);
    }
#pragma unroll
    for (int ks = 0; ks < 2; ++ks) {
      const int ko = (ks * 32 + quad * 8) ^ swz;
      s8v af[4], bfv[6];
#pragma unroll
      for (int mt = 0; mt < 4; ++mt)
        af[mt] = *(const s8v*)(&bc[(wm * 64 + mt * 16 + l15) * 64 + ko]);
#pragma unroll
      for (int nt = 0; nt < 6; ++nt)
        bfv[nt] = *(const s8v*)(&bc[(128 + wn * 96 + nt * 16 + l15) * 64 + ko]);
#pragma unroll
      for (int mt = 0; mt < 4; ++mt)
#pragma unroll
        for (int nt = 0; nt < 6; ++nt)
          acc1[mt][nt] = __builtin_amdgcn_mfma_f32_16x16x32_bf16(af[mt], bfv[nt], acc1[mt][nt], 0, 0, 0);
    }
    wait_vm0();
    __syncthreads();
  }

  // ==================== EPILOGUE 1: stencil/GELU/LN -> xaug (LDS) ==========
  for (int ck = 0; ck < 4; ++ck) {
    const int lo = ck * 31;
    // dump raw P rows [lo, lo+31) into sP1 (stride 388, col = seg*130 + c)
#pragma unroll
    for (int mt = 0; mt < 4; ++mt) {
      int rbase = wm * 64 + mt * 16 + quad * 4 - lo;
#pragma unroll
      for (int nt = 0; nt < 6; ++nt) {
        int gcol = wn * 96 + nt * 16;                 // 16-aligned, one seg
        int colp = (gcol >> 7) * 130 + (gcol & 127) + l15;
#pragma unroll
        for (int r = 0; r < 4; ++r) {
          int rr = rbase + r;
          if ((unsigned)rr < 31u) sP1[rr * 388 + colp] = acc1[mt][nt][r];
        }
      }
    }
    __syncthreads();
    // LN stats: 372 threads = (seg,row) x 4 lanes; seg-major (uniform-ish)
    if (tid < 372) {
      int seg = tid < 124 ? 0 : (tid < 248 ? 1 : 2);
      int rem = tid - seg * 124;
      int row = rem >> 2, q = rem & 3;
      float sum = 0.f, ss = 0.f;
#pragma unroll
      for (int i = 0; i < 32; ++i) {
        float v = stencil_gelu3(sP1, sBias, seg, row, q + 4 * i);
        sum += v; ss += v * v;
      }
      sum += __shfl_xor(sum, 1, 64); ss += __shfl_xor(ss, 1, 64);
      sum += __shfl_xor(sum, 2, 64); ss += __shfl_xor(ss, 2, 64);
      if (q == 0) {
        float mu = sum * (1.f / 128.f);
        sMu[seg * 31 + row] = mu;
        sRs[seg * 31 + row] = rsqrtf(ss * (1.f / 128.f) - mu * mu + 1e-5f);
      }
    }
    __syncthreads();
    // normalize + write xaug (paired bf16 -> b32 writes); seg compile-time
#pragma unroll
    for (int seg = 0; seg < 3; ++seg) {
      for (int idx = tid; idx < 31 * 64; idx += 512) {
        int row = idx >> 6, cp = (idx & 63) * 2;
        float v0 = stencil_gelu3(sP1, sBias, seg, row, cp);
        float v1 = stencil_gelu3(sP1, sBias, seg, row, cp + 1);
        float mu = sMu[seg * 31 + row], rs = sRs[seg * 31 + row];
        float o0 = (v0 - mu) * rs * sG[seg * 128 + cp]     + sLb[seg * 128 + cp];
        float o1 = (v1 - mu) * rs * sG[seg * 128 + cp + 1] + sLb[seg * 128 + cp + 1];
        unsigned int u = (unsigned int)f2bf(o0) | ((unsigned int)f2bf(o1) << 16);
        *(unsigned int*)(&xaug[(size_t)(lo + row) * 392 + seg * 128 + cp]) = u;
      }
    }
    __syncthreads();
  }

  // ==================== PHASE 2: GEMM2 (K=384, BK=32, N=256) ===============
  // A = xaug direct from LDS (stride 392 -> uniform banks). B = W2t staged:
  // tile [256][32] shorts = 16 slices of 16 rows x 64B; 2 slices per wave.
  f4v acc2[4][4];
#pragma unroll
  for (int mt = 0; mt < 4; ++mt)
#pragma unroll
    for (int nt = 0; nt < 4; ++nt) acc2[mt][nt] = (f4v){0.f, 0.f, 0.f, 0.f};
  {
    const int r2 = lane >> 2;                         // row in slice (0..15)
    const int c2 = ((lane & 3) ^ (r2 & 3)) * 8;       // pre-swizzled chunk
    const unsigned short* src2[2];
#pragma unroll
    for (int j = 0; j < 2; ++j)
      src2[j] = W2t + (size_t)((wv * 2 + j) * 16 + r2) * 384 + c2;
#pragma unroll
    for (int j = 0; j < 2; ++j) ld_lds16(src2[j], stg2 + (wv * 2 + j) * 512, lane);
    wait_vm0();
    __syncthreads();
    const int bko = (quad ^ (l15 & 3)) << 3;          // swizzled B chunk (shorts)
    for (int kt = 0; kt < 12; ++kt) {
      unsigned short* bc = stg2 + (kt & 1) * 8192;
      unsigned short* bn = stg2 + ((kt & 1) ^ 1) * 8192;
      if (kt < 11) {
#pragma unroll
        for (int j = 0; j < 2; ++j)
          ld_lds16(src2[j] + (kt + 1) * 32, bn + (wv * 2 + j) * 512, lane);
      }
      s8v af[4], bfv[4];
#pragma unroll
      for (int mt = 0; mt < 4; ++mt)
        af[mt] = *(const s8v*)(&xaug[(size_t)(wm * 64 + mt * 16 + l15) * 392 + kt * 32 + quad * 8]);
#pragma unroll
      for (int nt = 0; nt < 4; ++nt)
        bfv[nt] = *(const s8v*)(&bc[(wn * 64 + nt * 16 + l15) * 32 + bko]);
#pragma unroll
      for (int mt = 0; mt < 4; ++mt)
#pragma unroll
        for (int nt = 0; nt < 4; ++nt)
          acc2[mt][nt] = __builtin_amdgcn_mfma_f32_16x16x32_bf16(af[mt], bfv[nt], acc2[mt][nt], 0, 0, 0);
      wait_vm0();
      __syncthreads();
    }
  }

  // ==================== EPILOGUE 2: GELU + time-mean -> xlstm (LDS) ========
  for (int ck = 0; ck < 4; ++ck) {
    const int lo = ck * 31;
#pragma unroll
    for (int mt = 0; mt < 4; ++mt) {
      int rbase = wm * 64 + mt * 16 + quad * 4 - lo;
#pragma unroll
      for (int nt = 0; nt < 4; ++nt) {
        int col = wn * 64 + nt * 16 + l15;
#pragma unroll
        for (int r = 0; r < 4; ++r) {
          int rr = rbase + r;
          if ((unsigned)rr < 31u) sP2[rr * 260 + col] = acc2[mt][nt][r];
        }
      }
    }
    __syncthreads();
    for (int idx = tid; idx < 31 * 256; idx += 512) {   // gelu + bias in place
      int row = idx >> 8, col = idx & 255;
      sP2[row * 260 + col] = fgelu(sP2[row * 260 + col] + sL0b[col]);
    }
    __syncthreads();
    if (tid < 256) {                                    // per-(batch,col) mean
      float s = 0.f;
      for (int tr = 0; tr < 31; ++tr) s += sP2[tr * 260 + tid];
      sCM[tid] = s * (1.f / 31.f);
    }
    __syncthreads();
    for (int idx = tid; idx < 31 * 128; idx += 512) {   // subtract + pack
      int row = idx >> 7, cp = (idx & 127) * 2;
      float v0 = sP2[row * 260 + cp]     - sCM[cp];
      float v1 = sP2[row * 260 + cp + 1] - sCM[cp + 1];
      unsigned int u = (unsigned int)f2bf(v0) | ((unsigned int)f2bf(v1) << 16);
      *(unsigned int*)(&xlstm[(size_t)(lo + row) * 260 + cp]) = u;
    }
    __syncthreads();
  }

  // ==================== PHASE 3: GEMM3 (K=256, BK=64, N=512 in 2 passes) ===
  // A = xlstm from LDS (stride 260 -> uniform banks). B = Wiht staged:
  // tile [256][64] shorts = 32 slices of 8 rows x 128B; 4 slices per wave.
  f4v acc3[4][4];
  for (int p = 0; p < 2; ++p) {
    const unsigned short* src3[4];
#pragma unroll
    for (int j = 0; j < 4; ++j)
      src3[j] = Wiht + (size_t)(p * 256 + (wv * 4 + j) * 8 + subrow) * 256 + schunk8;
#pragma unroll
    for (int mt = 0; mt < 4; ++mt)
#pragma unroll
      for (int nt = 0; nt < 4; ++nt) acc3[mt][nt] = (f4v){0.f, 0.f, 0.f, 0.f};
#pragma unroll
    for (int j = 0; j < 4; ++j) ld_lds16(src3[j], stg3 + (wv * 4 + j) * 512, lane);
    wait_vm0();
    __syncthreads();
    for (int kt = 0; kt < 4; ++kt) {
      unsigned short* bc = stg3 + (kt & 1) * 16384;
      unsigned short* bn = stg3 + ((kt & 1) ^ 1) * 16384;
      if (kt < 3) {
#pragma unroll
        for (int j = 0; j < 4; ++j)
          ld_lds16(src3[j] + (kt + 1) * 64, bn + (wv * 4 + j) * 512, lane);
      }
#pragma unroll
      for (int ks = 0; ks < 2; ++ks) {
        const int ko = (ks * 32 + quad * 8) ^ swz;
        s8v af[4], bfv[4];
#pragma unroll
        for (int mt = 0; mt < 4; ++mt)
          af[mt] = *(const s8v*)(&xlstm[(size_t)(wm * 64 + mt * 16 + l15) * 260 + kt * 64 + ks * 32 + quad * 8]);
#pragma unroll
        for (int nt = 0; nt < 4; ++nt)
          bfv[nt] = *(const s8v*)(&bc[(wn * 64 + nt * 16 + l15) * 64 + ko]);
#pragma unroll
        for (int mt = 0; mt < 4; ++mt)
#pragma unroll
          for (int nt = 0; nt < 4; ++nt)
            acc3[mt][nt] = __builtin_amdgcn_mfma_f32_16x16x32_bf16(af[mt], bfv[nt], acc3[mt][nt], 0, 0, 0);
      }
      wait_vm0();
      __syncthreads();
    }
    // ---- EPILOGUE 3: +bias -> bf16 -> PRE (coalesced via sPb repack) ------
    for (int ck = 0; ck < 4; ++ck) {
      const int lo = ck * 31;
#pragma unroll
      for (int mt = 0; mt < 4; ++mt) {
        int rbase = wm * 64 + mt * 16 + quad * 4 - lo;
#pragma unroll
        for (int nt = 0; nt < 4; ++nt) {
          int col = wn * 64 + nt * 16 + l15;
          float bias = sB3[p * 256 + col];
#pragma unroll
          for (int r = 0; r < 4; ++r) {
            int rr = rbase + r;
            if ((unsigned)rr < 31u) sPb[rr * 264 + col] = f2bf(acc3[mt][nt][r] + bias);
          }
        }
      }
      __syncthreads();
      for (int u = tid; u < 992; u += 512) {            // 31 rows x 32 x 16B
        int row = u >> 5, cq = (u & 31) * 8;
        *(uint4*)(pre + (size_t)(rowBase + lo + row) * 512 + p * 256 + cq) =
            *(const uint4*)(&sPb[row * 264 + cq]);
      }
      __syncthreads();
    }
  }
}

// ===========================================================================
// k4: LSTM recurrence, one block = 16 batches x 1 direction; grid (256, 2)
// ===========================================================================
__global__ __launch_bounds__(256) void k4_lstm(
    const unsigned short* __restrict__ pre, const unsigned short* __restrict__ Whht,
    unsigned short* __restrict__ win) {
  __shared__ unsigned short sW[256 * 72];   // whh^T [n][k] padded
  __shared__ unsigned short sH[16 * 72];    // h bf16 [b][k] padded
  __shared__ float sG[16 * 260];            // gates fp32 [b][col]
  int tid = threadIdx.x;
  int dir = blockIdx.y;
  int b0  = blockIdx.x * 16;
  {                                         // stage whh^T for this dir
    const unsigned short* src = Whht + dir * 16384;
#pragma unroll
    for (int c = 0; c < 8; ++c) {
      int id = tid + c * 256;               // 2048 chunks of 8 bf16
      int row = id >> 3, kc = (id & 7) * 8;
      uint4 v = *(const uint4*)(src + row * 64 + kc);
      *(uint4*)(&sW[row * 72 + kc]) = v;
    }
  }
  for (int i = tid; i < 16 * 72; i += 256) sH[i] = 0;
  __syncthreads();

  const int lane = tid & 63, wv = tid >> 6, l15 = lane & 15, quad = lane >> 4;
  const int eb = tid >> 4, jb = (tid & 15) * 4;   // elementwise: batch, j-quad
  float cs[4] = {0.f, 0.f, 0.f, 0.f};

  // prefetch t=0's pre row
  int tt0 = dir ? 30 : 0;
  const unsigned short* pbase = pre + ((size_t)(b0 + eb) * 31) * 512 + dir * 256;
  ushort4 pi = *(const ushort4*)(pbase + tt0 * 512 + jb);
  ushort4 pf = *(const ushort4*)(pbase + tt0 * 512 + 64 + jb);
  ushort4 pg = *(const ushort4*)(pbase + tt0 * 512 + 128 + jb);
  ushort4 po = *(const ushort4*)(pbase + tt0 * 512 + 192 + jb);

  for (int t = 0; t < 31; ++t) {
    f4v acc[4];
#pragma unroll
    for (int nt = 0; nt < 4; ++nt) acc[nt] = (f4v){0.f, 0.f, 0.f, 0.f};
#pragma unroll
    for (int ks = 0; ks < 2; ++ks) {
      s8v af = *(const s8v*)(&sH[l15 * 72 + ks * 32 + quad * 8]);
#pragma unroll
      for (int nt = 0; nt < 4; ++nt) {
        int n = wv * 64 + nt * 16 + l15;
        s8v bfv = *(const s8v*)(&sW[n * 72 + ks * 32 + quad * 8]);
        acc[nt] = __builtin_amdgcn_mfma_f32_16x16x32_bf16(af, bfv, acc[nt], 0, 0, 0);
      }
    }
#pragma unroll
    for (int nt = 0; nt < 4; ++nt)
#pragma unroll
      for (int r = 0; r < 4; ++r)
        sG[(quad * 4 + r) * 260 + wv * 64 + nt * 16 + l15] = acc[nt][r];

    ushort4 ni, nf, ng, no;                 // prefetch t+1 before the barrier
    if (t < 30) {
      int ttn = dir ? 29 - t : t + 1;
      ni = *(const ushort4*)(pbase + ttn * 512 + jb);
      nf = *(const ushort4*)(pbase + ttn * 512 + 64 + jb);
      ng = *(const ushort4*)(pbase + ttn * 512 + 128 + jb);
      no = *(const ushort4*)(pbase + ttn * 512 + 192 + jb);
    }
    __syncthreads();

    int tt = dir ? 30 - t : t;
    const float* g = &sG[eb * 260];
    float hv[4];
#pragma unroll
    for (int jj = 0; jj < 4; ++jj) {
      int j = jb + jj;
      float vi = g[j]       + bf2f(jj == 0 ? pi.x : jj == 1 ? pi.y : jj == 2 ? pi.z : pi.w);
      float vf = g[64 + j]  + bf2f(jj == 0 ? pf.x : jj == 1 ? pf.y : jj == 2 ? pf.z : pf.w);
      float vg = g[128 + j] + bf2f(jj == 0 ? pg.x : jj == 1 ? pg.y : jj == 2 ? pg.z : pg.w);
      float vo = g[192 + j] + bf2f(jj == 0 ? po.x : jj == 1 ? po.y : jj == 2 ? po.z : po.w);
      float cc = fsig(vf) * cs[jj] + fsig(vi) * ftanh(vg);
      cs[jj] = cc;
      hv[jj] = fsig(vo) * ftanh(cc);
    }
    ushort4 hb;
    hb.x = f2bf(hv[0]); hb.y = f2bf(hv[1]); hb.z = f2bf(hv[2]); hb.w = f2bf(hv[3]);
    *(ushort4*)(&sH[eb * 72 + jb]) = hb;
    if (tt >= 10 && tt <= 20)
      *(ushort4*)(win + ((size_t)(b0 + eb) * 11 + (tt - 10)) * 128 + dir * 64 + jb) = hb;
    if (t < 30) { pi = ni; pf = nf; pg = ng; po = no; }
    __syncthreads();
  }
}

// ===========================================================================
// k5: attention over window + lin2 + gated blend with linear_logits -> d_out
// ===========================================================================
__global__ __launch_bounds__(256) void k5_attn(
    const unsigned short* __restrict__ win, const float* __restrict__ attn_w,
    const float* __restrict__ attn_b, const float* __restrict__ attn_t,
    const float* __restrict__ lin2_w, const float* __restrict__ lin2_b,
    const float* __restrict__ linlog, const float* __restrict__ gate,
    float* __restrict__ out) {
  __shared__ unsigned short sWin[176 * 128];
  __shared__ float sAw[128];
  __shared__ float sSc[176];
  __shared__ float sAtt[16 * 128];
  int tid = threadIdx.x;
  int b0  = blockIdx.x * 16;
#pragma unroll
  for (int c = 0; c < 11; ++c) {              // stage 16 batches x 11 t x 128 ch
    int id = tid + c * 256;
    int row = id >> 4, kc = (id & 15) * 8;
    uint4 v = *(const uint4*)(win + ((size_t)b0 * 11 + row) * 128 + kc);
    *(uint4*)(&sWin[row * 128 + kc]) = v;
  }
  if (tid < 128) sAw[tid] = attn_w[tid];
  __syncthreads();
  if (tid < 176) {                            // scores
    int b = tid / 11, wt = tid - b * 11;
    const unsigned short* w = &sWin[(b * 11 + wt) * 128];
    float dot = 0.f;
    for (int ch = 0; ch < 128; ++ch) dot += bf2f(w[ch]) * sAw[ch];
    float temp = logf(1.f + __expf(attn_t[0])) + 0.001f;
    sSc[tid] = (dot + attn_b[0]) / temp;
  }
  __syncthreads();
  if (tid < 16) {                             // softmax over 11
    float m = -1e30f;
    for (int wt = 0; wt < 11; ++wt) m = fmaxf(m, sSc[tid * 11 + wt]);
    float e[11], sum = 0.f;
    for (int wt = 0; wt < 11; ++wt) { e[wt] = __expf(sSc[tid * 11 + wt] - m); sum += e[wt]; }
    float inv = __fdividef(1.f, sum);
    for (int wt = 0; wt < 11; ++wt) sSc[tid * 11 + wt] = e[wt] * inv;
  }
  __syncthreads();
#pragma unroll
  for (int p = 0; p < 8; ++p) {               // attended (also an output)
    int task = tid + p * 256;
    int b = task >> 7, ch = task & 127;
    float a = 0.f;
    for (int wt = 0; wt < 11; ++wt)
      a += sSc[b * 11 + wt] * bf2f(sWin[(b * 11 + wt) * 128 + ch]);
    sAtt[b * 128 + ch] = a;
    out[49152 + (size_t)(b0 + b) * 128 + ch] = a;
  }
  __syncthreads();
  if (tid < 192) {                            // lstm_logits + gated blend
    int b = tid / 12, o = tid - b * 12;
    float dot = 0.f;
    for (int ch = 0; ch < 128; ++ch) dot += sAtt[b * 128 + ch] * lin2_w[ch * 12 + o];
    dot += lin2_b[o];
    float lin = linlog[(size_t)(b0 + b) * 12 + o];
    float gg = fsig(gate[0]);
    out[(size_t)(b0 + b) * 12 + o] = lin + gg * (dot - lin);
  }
}

// ===========================================================================
extern "C" void kernel_launch(void* const* d_in, const int* in_sizes, int n_in,
                              void* d_out, int out_size, void* d_ws, size_t ws_size,
                              hipStream_t stream) {
  const float* x       = (const float*)d_in[0];
  const float* cls_w   = (const float*)d_in[1];
  const float* cls_b   = (const float*)d_in[2];
  const float* delta_w = (const float*)d_in[3];
  const float* delta_b = (const float*)d_in[4];
  const float* acc_w   = (const float*)d_in[5];
  const float* acc_b   = (const float*)d_in[6];
  const float* cls_g   = (const float*)d_in[7];
  const float* cls_be  = (const float*)d_in[8];
  const float* del_g   = (const float*)d_in[9];
  const float* del_be  = (const float*)d_in[10];
  const float* accg    = (const float*)d_in[11];
  const float* accbe   = (const float*)d_in[12];
  const float* lin0_w  = (const float*)d_in[13];
  const float* lin0_b  = (const float*)d_in[14];
  const float* gate    = (const float*)d_in[15];
  const float* attn_w  = (const float*)d_in[16];
  const float* attn_b  = (const float*)d_in[17];
  const float* attn_t  = (const float*)d_in[18];
  const float* lin1_w  = (const float*)d_in[19];
  const float* lin1_b  = (const float*)d_in[20];
  const float* lin2_w  = (const float*)d_in[21];
  const float* lin2_b  = (const float*)d_in[22];
  const float* wih_f   = (const float*)d_in[23];
  const float* whh_f   = (const float*)d_in[24];
  const float* b_f     = (const float*)d_in[25];
  const float* wih_r   = (const float*)d_in[26];
  const float* whh_r   = (const float*)d_in[27];
  const float* b_r     = (const float*)d_in[28];

  char* ws = (char*)d_ws;
  unsigned short* W1t   = (unsigned short*)(ws + OFF_W1T);
  unsigned short* W2t   = (unsigned short*)(ws + OFF_W2T);
  unsigned short* Wiht  = (unsigned short*)(ws + OFF_WIHT);
  unsigned short* Whht  = (unsigned short*)(ws + OFF_WHHT);
  unsigned short* XS    = (unsigned short*)(ws + OFF_XS);
  float*          XW    = (float*)(ws + OFF_XW);
  float*          LL    = (float*)(ws + OFF_LL);
  unsigned short* WIN   = (unsigned short*)(ws + OFF_WIN);
  unsigned short* PRE   = (unsigned short*)(ws + OFF_PRE);
  float* out = (float*)d_out;

  k0_prep<<<2176, 256, 0, stream>>>(cls_w, delta_w, acc_w, lin0_w, wih_f, wih_r,
                                    whh_f, whh_r, (unsigned short*)ws);
  k1_ema<<<12288, 256, 0, stream>>>(x, XS, XW);
  k1b_linlog<<<4096, 64, 0, stream>>>(XW, lin1_w, lin1_b, LL);
  k2_mega<<<1024, 512, 0, stream>>>(XS, W1t, W2t, Wiht, cls_b, delta_b, acc_b,
                                    cls_g, cls_be, del_g, del_be, accg, accbe,
                                    lin0_b, b_f, b_r, PRE);
  k4_lstm<<<dim3(256, 2), 256, 0, stream>>>(PRE, Whht, WIN);
  k5_attn<<<256, 256, 0, stream>>>(WIN, attn_w, attn_b, attn_t, lin2_w, lin2_b,
                                   LL, gate, out);
}

// Round 3
// 1179.601 us; speedup vs baseline: 1.1800x; 1.1800x over previous
//
#include <hip/hip_runtime.h>
#include <cstdint>
#include <cstddef>

// ---------------------------------------------------------------------------
// ClassifierLSTMDeltas on gfx950 — bf16 MFMA pipeline, round 6.
// Shapes: B=4096 T=31 C=768 BD=128 AUG=384 HID=256 H=64 O=12
// Round-6: revert round-5 mega (regressed: acc spills -> WRITE 303MB, and
// 8-wave occupancy). Base = round-4 (1101us). Changes:
//  - k3+k3b fused into k3c using the PROVEN round-4 k2 skeleton: 1024 thr /
//    16 waves, acc[4][2] per phase (32 VGPR, no spill), 2-phase dbuf
//    pre-swizzled global_load_lds staging. xlstm lives in LDS between
//    GEMM2 and GEMM3 -> kills XLSTM HBM traffic (65MB w + 260MB r).
//  - k1_ema vectorized: float2 loads + packed-b32 bf16 stores (was 2B
//    scalar stores, G13 violation).
// k0/k1b/k2_aug/k4/k5 identical to round-4.
// ---------------------------------------------------------------------------

typedef short s8v __attribute__((ext_vector_type(8)));   // 8 bf16 (4 VGPR) MFMA frag
typedef float f4v __attribute__((ext_vector_type(4)));   // MFMA acc

#if defined(__has_builtin)
#if __has_builtin(__builtin_amdgcn_global_load_lds)
#define HAVE_GLL 1
#endif
#endif
#ifndef HAVE_GLL
#define HAVE_GLL 0
#endif

__device__ __forceinline__ unsigned short f2bf(float f) {
  union { float f; unsigned int u; } v; v.f = f;
  unsigned int u = v.u;
  return (unsigned short)((u + 0x7fffu + ((u >> 16) & 1u)) >> 16);  // RNE
}
__device__ __forceinline__ float bf2f(unsigned short h) {
  union { unsigned int u; float f; } v; v.u = ((unsigned int)h) << 16;
  return v.f;
}
__device__ __forceinline__ float fsig(float x) {
  return __fdividef(1.f, 1.f + __expf(-x));
}
__device__ __forceinline__ float ftanh(float x) {
  return 1.f - __fdividef(2.f, 1.f + __expf(2.f * x));
}
__device__ __forceinline__ float fgelu(float x) {          // exact gelu (erf)
  return 0.5f * x * (1.f + erff(x * 0.70710678118654752f));
}

// async 16B global->LDS. ldsU is the WAVE-UNIFORM destination base; HW lands
// lane i at ldsU + i*16 (per cdna_hip_programming §5 caveat). g is per-lane.
__device__ __forceinline__ void ld_lds16(const unsigned short* g,
                                         unsigned short* ldsU, int lane) {
#if HAVE_GLL
  __builtin_amdgcn_global_load_lds(
      (__attribute__((address_space(1))) void*)(uintptr_t)(const void*)g,
      (__attribute__((address_space(3))) void*)(unsigned int)(uintptr_t)(void*)ldsU,
      16, 0, 0);
#else
  *(uint4*)(ldsU + lane * 8) = *(const uint4*)g;
#endif
}
__device__ __forceinline__ void wait_vm0() {
#if HAVE_GLL
  __builtin_amdgcn_s_waitcnt(0x0F70);   // vmcnt(0), lgkm/exp unconstrained
#endif
}

// ---- workspace layout (bytes) ---------------------------------------------
#define OFF_W1T   0u            // [384][768] bf16   (cls|delta|acc transposed)
#define OFF_W2T   589824u       // [256][384] bf16   (lin0 transposed)
#define OFF_WIHT  786432u       // [512][256] bf16   (wih_f rows 0-255, wih_r 256-511)
#define OFF_WHHT  1048576u      // [2][256][64] bf16 (whh transposed per dir)
#define OFF_XS    1114112u      // [126976][768] bf16 x_smooth; reused as PRE [126976][512]
#define OFF_XW    196149248u    // [4096][768] f32 window mean
#define OFF_LL    208732160u    // [4096][12] f32 linear_logits
#define OFF_WIN   208928768u    // [4096][11][128] bf16 lstm window
#define OFF_XAUG  220463104u    // [126976][384] bf16

// ===========================================================================
// k0: transpose + bf16-convert all GEMM weights into [N][K] layout
// ===========================================================================
__global__ __launch_bounds__(256) void k0_prep(
    const float* __restrict__ cls_w, const float* __restrict__ delta_w,
    const float* __restrict__ acc_w, const float* __restrict__ lin0_w,
    const float* __restrict__ wih_f, const float* __restrict__ wih_r,
    const float* __restrict__ whh_f, const float* __restrict__ whh_r,
    unsigned short* __restrict__ ws) {
  int i = blockIdx.x * 256 + threadIdx.x;        // 557056 total elements
  if (i < 294912) {                              // W1t[n][k], n in [0,384)
    int n = i / 768, k = i - n * 768;
    int seg = n >> 7, nn = n & 127;
    const float* w = seg == 0 ? cls_w : (seg == 1 ? delta_w : acc_w);
    ws[i] = f2bf(w[k * 128 + nn]);
  } else if (i < 393216) {                       // W2t[n][k], n in [0,256), k in [0,384)
    int j = i - 294912;
    int n = j / 384, k = j - n * 384;
    ws[i] = f2bf(lin0_w[k * 256 + n]);
  } else if (i < 524288) {                       // Wiht[n][k], n in [0,512), k in [0,256)
    int j = i - 393216;
    int n = j >> 8, k = j & 255;
    ws[i] = f2bf(n < 256 ? wih_f[k * 256 + n] : wih_r[k * 256 + (n - 256)]);
  } else if (i < 557056) {                       // Whht[d][n][k]
    int j = i - 524288;
    int d = j >> 14, rem = j & 16383;
    int n = rem >> 6, k = rem & 63;
    const float* w = d ? whh_r : whh_f;
    ws[i] = f2bf(w[k * 256 + n]);
  }
}

// ===========================================================================
// k1: EMA scan over T per (b, channel-pair); float2 loads, packed b32 stores
// ===========================================================================
__global__ __launch_bounds__(256) void k1_ema(
    const float* __restrict__ x, unsigned short* __restrict__ xs,
    float* __restrict__ xw) {
  int gid = blockIdx.x * 256 + threadIdx.x;      // b*384 + cp
  int b = gid / 384;
  int cp = gid - b * 384;
  size_t base = (size_t)b * 31 * 768 + cp * 2;
  float2 s = *(const float2*)(x + base);
  *(unsigned int*)(xs + base) =
      (unsigned int)f2bf(s.x) | ((unsigned int)f2bf(s.y) << 16);
  float w0 = 0.f, w1 = 0.f;
#pragma unroll
  for (int t = 1; t < 31; ++t) {
    float2 xv = *(const float2*)(x + base + t * 768);
    s.x += 0.3f * (xv.x - s.x);
    s.y += 0.3f * (xv.y - s.y);
    *(unsigned int*)(xs + base + t * 768) =
        (unsigned int)f2bf(s.x) | ((unsigned int)f2bf(s.y) << 16);
    if (t >= 10 && t <= 20) { w0 += s.x; w1 += s.y; }
  }
  float2 wm; wm.x = w0 * (1.f / 11.f); wm.y = w1 * (1.f / 11.f);
  *(float2*)(xw + (size_t)b * 768 + cp * 2) = wm;
}

// ===========================================================================
// k1b: linear_logits = xw_mean @ lin1_w + lin1_b   (one wave per batch row)
// ===========================================================================
__global__ __launch_bounds__(64) void k1b_linlog(
    const float* __restrict__ xw, const float* __restrict__ lin1_w,
    const float* __restrict__ lin1_b, float* __restrict__ ll) {
  int b = blockIdx.x;
  int lane = threadIdx.x;
  float p[12];
#pragma unroll
  for (int o = 0; o < 12; ++o) p[o] = 0.f;
  for (int k = lane; k < 768; k += 64) {
    float xv = xw[b * 768 + k];
    const float* w = lin1_w + k * 12;
#pragma unroll
    for (int o = 0; o < 12; ++o) p[o] += xv * w[o];
  }
#pragma unroll
  for (int o = 0; o < 12; ++o) {
    float v = p[o];
#pragma unroll
    for (int s = 1; s < 64; s <<= 1) v += __shfl_xor(v, s, 64);
    p[o] = v;
  }
  if (lane == 0) {
#pragma unroll
    for (int o = 0; o < 12; ++o) ll[b * 12 + o] = p[o] + lin1_b[o];
  }
}

// time-stencil (reflect-pad derivative streams) + bias + exact GELU.
// sP is [31][390] f32, one batch, seg-padded cols (seg*130 + c).
__device__ __forceinline__ float stencil_gelu3(const float* sP, const float* sBias,
                                               int seg, int t, int c) {
  const float* p = sP + t * 390 + seg * 130 + c;
  float v;
  if (seg == 0) {
    v = p[0];
  } else if (seg == 1) {                          // delta: s_t - s_{t-1}; t=0: s0-s1
    v = (t == 0) ? (p[0] - p[390]) : (p[0] - p[-390]);
  } else {                                        // acc: s_t-2s_{t-1}+s_{t-2}; edges reflect
    if (t == 0)      v = p[0] - 2.f * p[390] + p[780];
    else if (t == 1) v = 2.f * (p[0] - p[-390]);
    else             v = p[0] - 2.f * p[-390] + p[-780];
  }
  return fgelu(v + sBias[seg * 128 + c]);
}

// ===========================================================================
// k2: P = x_smooth @ [cls|delta|acc] (128x384 tile) -> stencil -> GELU ->
// LayerNorm(128 per seg) -> x_aug.  1024 threads = 16 waves (2M x 8N), each
// wave owns 64x48 (acc[4][3]).  Double-buffered 64KB staging, 2-phase
// pipeline, XOR-swizzled LDS (pre-swizzled global source, swizzled ds_read).
// Grid: 1024 blocks x (4 batches x 31 t = 124 rows of 128-row tile).
// [round-4 kernel, unchanged — measured 261us / MfmaUtil 12.2 / occ 46.5]
// ===========================================================================
__global__ __launch_bounds__(1024) void k2_aug(
    const unsigned short* __restrict__ xs, const unsigned short* __restrict__ W1t,
    const float* __restrict__ cls_b, const float* __restrict__ delta_b,
    const float* __restrict__ acc_b,
    const float* __restrict__ g0, const float* __restrict__ be0,
    const float* __restrict__ g1, const float* __restrict__ be1,
    const float* __restrict__ g2, const float* __restrict__ be2,
    unsigned short* __restrict__ xaug) {
  __shared__ __align__(16) char smem[131072];    // buf0 | buf1 (64KB each)
  unsigned short* buf0 = (unsigned short*)smem;
  unsigned short* buf1 = (unsigned short*)(smem + 65536);
  float* sP    = (float*)smem;                   // [31][390] chunk scratch (aliases buf0)
  float* sBias = (float*)(smem + 65536);         // [384]  (aliases buf1)
  float* sG    = sBias + 384;                    // [384]
  float* sLb   = sG + 384;                       // [384]
  float* sMu   = sLb + 384;                      // [3][31]
  float* sRs   = sMu + 93;                       // [3][31]

  const int tid  = threadIdx.x;
  const int lane = tid & 63;
  const int wv   = tid >> 6;          // 0..15
  const int l15  = lane & 15;
  const int quad = lane >> 4;
  const int wm   = wv >> 3;           // 0..1  (M half)
  const int wn   = wv & 7;            // 0..7  (N slot, 48 cols each)
  const int rowBase = blockIdx.x * 124;

  const int subrow = lane >> 3;
  const int schunk = ((lane & 7) ^ subrow) * 8;
  const unsigned short* src[4];
#pragma unroll
  for (int j = 0; j < 4; ++j) {
    int slice = wv * 4 + j;
    int row = slice * 8 + subrow;     // 0..511
    src[j] = (row < 128)
        ? xs + (size_t)(rowBase + (row < 124 ? row : 123)) * 768 + schunk
        : W1t + (size_t)(row - 128) * 768 + schunk;
  }

  f4v acc[4][3];
#pragma unroll
  for (int mt = 0; mt < 4; ++mt)
#pragma unroll
    for (int nt = 0; nt < 3; ++nt) acc[mt][nt] = (f4v){0.f, 0.f, 0.f, 0.f};

  const int swz = (l15 & 7) << 3;     // read-side XOR (shorts), self-inverse

  // prologue: stage kt=0 into buf0
#pragma unroll
  for (int j = 0; j < 4; ++j) ld_lds16(src[j], buf0 + (wv * 4 + j) * 512, lane);
  wait_vm0();
  __syncthreads();

  for (int kt = 0; kt < 12; ++kt) {
    unsigned short* bc = (kt & 1) ? buf1 : buf0;
    unsigned short* bn = (kt & 1) ? buf0 : buf1;
    if (kt < 11) {                    // issue next tile BEFORE compute (T3)
#pragma unroll
      for (int j = 0; j < 4; ++j)
        ld_lds16(src[j] + (kt + 1) * 64, bn + (wv * 4 + j) * 512, lane);
    }
#pragma unroll
    for (int ks = 0; ks < 2; ++ks) {
      s8v af[4], bfv[3];
      const int ko = (ks * 32 + quad * 8) ^ swz;
#pragma unroll
      for (int mt = 0; mt < 4; ++mt)
        af[mt] = *(const s8v*)(&bc[(wm * 64 + mt * 16 + l15) * 64 + ko]);
#pragma unroll
      for (int nt = 0; nt < 3; ++nt)
        bfv[nt] = *(const s8v*)(&bc[(128 + wn * 48 + nt * 16 + l15) * 64 + ko]);
#pragma unroll
      for (int mt = 0; mt < 4; ++mt)
#pragma unroll
        for (int nt = 0; nt < 3; ++nt)
          acc[mt][nt] = __builtin_amdgcn_mfma_f32_16x16x32_bf16(af[mt], bfv[nt], acc[mt][nt], 0, 0, 0);
    }
    wait_vm0();                       // next tile's loads have landed
    __syncthreads();                  // all waves done reading bc
  }

  // ---- epilogue: 4 chunks of 31 rows (one batch each) ----------------------
  if (tid < 384) {                    // per-col constants into buf1 alias
    int seg = tid >> 7, c = tid & 127;
    sBias[tid] = seg == 0 ? cls_b[c] : (seg == 1 ? delta_b[c] : acc_b[c]);
    sG[tid]    = seg == 0 ? g0[c]    : (seg == 1 ? g1[c]    : g2[c]);
    sLb[tid]   = seg == 0 ? be0[c]   : (seg == 1 ? be1[c]   : be2[c]);
  }

#pragma unroll
  for (int ck = 0; ck < 4; ++ck) {
    int lo = ck * 31;
    // dump this chunk's acc rows into sP (seg-padded col = seg*130 + c)
#pragma unroll
    for (int mt = 0; mt < 4; ++mt) {
      int rbase = wm * 64 + mt * 16 + quad * 4 - lo;
#pragma unroll
      for (int nt = 0; nt < 3; ++nt) {
        int gcol = wn * 48 + nt * 16;               // 16-aligned, single seg
        int colp = (gcol >> 7) * 130 + (gcol & 127) + l15;
#pragma unroll
        for (int r = 0; r < 4; ++r) {
          int rr = rbase + r;
          if ((unsigned)rr < 31u) sP[rr * 390 + colp] = acc[mt][nt][r];
        }
      }
    }
    __syncthreads();
    // LN stats: 744 threads, seg-major so branches stay near-wave-uniform
    if (tid < 744) {
      int seg = tid < 248 ? 0 : (tid < 496 ? 1 : 2);
      int rem = tid - seg * 248;
      int row = rem >> 3, q = rem & 7;              // 8 lanes per (seg,row)
      float sum = 0.f, ss = 0.f;
#pragma unroll
      for (int i = 0; i < 16; ++i) {
        float v = stencil_gelu3(sP, sBias, seg, row, q + 8 * i);
        sum += v; ss += v * v;
      }
      sum += __shfl_xor(sum, 1, 64); ss += __shfl_xor(ss, 1, 64);
      sum += __shfl_xor(sum, 2, 64); ss += __shfl_xor(ss, 2, 64);
      sum += __shfl_xor(sum, 4, 64); ss += __shfl_xor(ss, 4, 64);
      if (q == 0) {
        float mu = sum * (1.f / 128.f);
        sMu[seg * 31 + row] = mu;
        sRs[seg * 31 + row] = rsqrtf(ss * (1.f / 128.f) - mu * mu + 1e-5f);
      }
    }
    __syncthreads();
    // normalize + write x_aug; seg compile-time (no divergence)
#pragma unroll
    for (int seg = 0; seg < 3; ++seg) {
      for (int idx = tid; idx < 31 * 128; idx += 1024) {
        int row = idx >> 7, c = idx & 127;
        float v = stencil_gelu3(sP, sBias, seg, row, c);
        float o = (v - sMu[seg * 31 + row]) * sRs[seg * 31 + row]
                  * sG[seg * 128 + c] + sLb[seg * 128 + c];
        xaug[(size_t)(rowBase + lo + row) * 384 + seg * 128 + c] = f2bf(o);
      }
    }
    __syncthreads();
  }
}

// ===========================================================================
// k3c: fused k3+k3b. Per block = 124 rows (4 batches x 31 t), 1024 threads
// = 16 waves (2M x 8N, wave 64x32, acc[4][2] = 32 VGPR -> no spill).
//   GEMM2: P2 = xaug @ W2t^T (K=384, N=256), staged dbuf 2x48KB
//   Ep2  : GELU+bias, per-batch time-mean subtract -> xlstm [124][260] LDS
//   GEMM3: P3 = xlstm @ Wiht^T (K=256, N=512 in 2 passes), B staged 2x32KB
//   Ep3  : +bias -> bf16 -> PRE (coalesced 16B stores via sPb repack)
// LDS: stg2 dbuf @0 (96KB) | xlstm @0 (63KB, after GEMM2) | stg3 @65536
// (64KB) | sPb @65536 (16.4KB, after each GEMM3 pass) | sP2 @98304 (31.5KB,
// ep2 only) | consts @131072 (4KB). Peak 135168 -> 1 block/CU, 16 waves.
// ===========================================================================
__global__ __launch_bounds__(1024) void k3c_fused(
    const unsigned short* __restrict__ xaug, const unsigned short* __restrict__ W2t,
    const unsigned short* __restrict__ Wiht, const float* __restrict__ lin0_b,
    const float* __restrict__ b_f, const float* __restrict__ b_r,
    unsigned short* __restrict__ pre) {
  __shared__ __align__(16) char smem[135168];
  unsigned short* stg2  = (unsigned short*)smem;            // 2 x 48KB
  unsigned short* xlstm = (unsigned short*)smem;            // [124][260] bf16
  unsigned short* stg3  = (unsigned short*)(smem + 65536);  // 2 x 32KB
  unsigned short* sPb   = (unsigned short*)(smem + 65536);  // [31][264] bf16
  float*          sP2   = (float*)(smem + 98304);           // [31][260] f32
  float* sL0b = (float*)(smem + 131072);                    // [256]
  float* sB3  = sL0b + 256;                                 // [512]
  float* sCM  = sB3 + 512;                                  // [256]

  const int tid  = threadIdx.x;
  const int lane = tid & 63;
  const int wv   = tid >> 6;            // 0..15
  const int l15  = lane & 15;
  const int quad = lane >> 4;
  const int wm   = wv >> 3;             // 0..1  M half
  const int wn   = wv & 7;              // 0..7  N slot (32 cols each)
  const int rowBase = blockIdx.x * 124;

  // constants (consumed only after multiple barriers)
  if (tid < 256) sL0b[tid] = lin0_b[tid];
  else if (tid < 768) {
    int i = tid - 256;
    sB3[i] = i < 256 ? b_f[i] : b_r[i - 256];
  }

  const int subrow  = lane >> 3;                 // 0..7 row within slice
  const int schunk8 = ((lane & 7) ^ subrow) * 8; // pre-swizzled source chunk
  const int swz     = (l15 & 7) << 3;            // read-side XOR (shorts)

  // ==================== GEMM2 (K=384, BK=64, N=256) ========================
  // staged tile: [A rows 0..127 | B rows 0..255] = 384 rows x 64 shorts =
  // 48 slices of 1KB; wave wv owns slices 3wv..3wv+2.
  const unsigned short* src2[3];
#pragma unroll
  for (int j = 0; j < 3; ++j) {
    int row = (wv * 3 + j) * 8 + subrow;         // 0..383
    src2[j] = (row < 128)
        ? xaug + (size_t)(rowBase + (row < 124 ? row : 123)) * 384 + schunk8
        : W2t + (size_t)(row - 128) * 384 + schunk8;
  }
  f4v acc2[4][2];
#pragma unroll
  for (int mt = 0; mt < 4; ++mt)
#pragma unroll
    for (int nt = 0; nt < 2; ++nt) acc2[mt][nt] = (f4v){0.f, 0.f, 0.f, 0.f};

#pragma unroll
  for (int j = 0; j < 3; ++j) ld_lds16(src2[j], stg2 + (wv * 3 + j) * 512, lane);
  wait_vm0();
  __syncthreads();

  for (int kt = 0; kt < 6; ++kt) {
    unsigned short* bc = stg2 + (kt & 1) * 24576;
    unsigned short* bn = stg2 + ((kt & 1) ^ 1) * 24576;
    if (kt < 5) {
#pragma unroll
      for (int j = 0; j < 3; ++j)
        ld_lds16(src2[j] + (kt + 1) * 64, bn + (wv * 3 + j) * 512, lane);
    }
#pragma unroll
    for (int ks = 0; ks < 2; ++ks) {
      const int ko = (ks * 32 + quad * 8) ^ swz;
      s8v af[4], bfv[2];
#pragma unroll
      for (int mt = 0; mt < 4; ++mt)
        af[mt] = *(const s8v*)(&bc[(wm * 64 + mt * 16 + l15) * 64 + ko]);
#pragma unroll
      for (int nt = 0; nt < 2; ++nt)
        bfv[nt] = *(const s8v*)(&bc[(128 + wn * 32 + nt * 16 + l15) * 64 + ko]);
#pragma unroll
      for (int mt = 0; mt < 4; ++mt)
#pragma unroll
        for (int nt = 0; nt < 2; ++nt)
          acc2[mt][nt] = __builtin_amdgcn_mfma_f32_16x16x32_bf16(af[mt], bfv[nt], acc2[mt][nt], 0, 0, 0);
    }
    wait_vm0();
    __syncthreads();
  }

  // ==================== EP2: GELU + time-mean -> xlstm (LDS) ===============
  for (int ck = 0; ck < 4; ++ck) {
    const int lo = ck * 31;
#pragma unroll
    for (int mt = 0; mt < 4; ++mt) {
      int rbase = wm * 64 + mt * 16 + quad * 4 - lo;
#pragma unroll
      for (int nt = 0; nt < 2; ++nt) {
        int col = wn * 32 + nt * 16 + l15;
#pragma unroll
        for (int r = 0; r < 4; ++r) {
          int rr = rbase + r;
          if ((unsigned)rr < 31u) sP2[rr * 260 + col] = acc2[mt][nt][r];
        }
      }
    }
    __syncthreads();
    for (int idx = tid; idx < 31 * 256; idx += 1024) {  // gelu + bias in place
      int row = idx >> 8, col = idx & 255;
      sP2[row * 260 + col] = fgelu(sP2[row * 260 + col] + sL0b[col]);
    }
    __syncthreads();
    if (tid < 256) {                                    // per-(batch,col) mean
      float s = 0.f;
      for (int tr = 0; tr < 31; ++tr) s += sP2[tr * 260 + tid];
      sCM[tid] = s * (1.f / 31.f);
    }
    __syncthreads();
    for (int idx = tid; idx < 31 * 128; idx += 1024) {  // subtract + pack
      int row = idx >> 7, cp = (idx & 127) * 2;
      float v0 = sP2[row * 260 + cp]     - sCM[cp];
      float v1 = sP2[row * 260 + cp + 1] - sCM[cp + 1];
      unsigned int u = (unsigned int)f2bf(v0) | ((unsigned int)f2bf(v1) << 16);
      *(unsigned int*)(&xlstm[(size_t)(lo + row) * 260 + cp]) = u;
    }
    __syncthreads();
  }

  // ==================== GEMM3 (K=256, BK=64, N=512 in 2 passes) ============
  // A = xlstm LDS (stride 260; rows 124..127 read garbage -> outputs unused).
  // B = Wiht staged: [256][64] per K-tile = 32 slices; wave owns 2.
  for (int p = 0; p < 2; ++p) {
    const unsigned short* src3[2];
#pragma unroll
    for (int j = 0; j < 2; ++j) {
      int row = (wv * 2 + j) * 8 + subrow;       // 0..255
      src3[j] = Wiht + (size_t)(p * 256 + row) * 256 + schunk8;
    }
    f4v acc3[4][2];
#pragma unroll
    for (int mt = 0; mt < 4; ++mt)
#pragma unroll
      for (int nt = 0; nt < 2; ++nt) acc3[mt][nt] = (f4v){0.f, 0.f, 0.f, 0.f};
#pragma unroll
    for (int j = 0; j < 2; ++j) ld_lds16(src3[j], stg3 + (wv * 2 + j) * 512, lane);
    wait_vm0();
    __syncthreads();
    for (int kt = 0; kt < 4; ++kt) {
      unsigned short* bc = stg3 + (kt & 1) * 16384;
      unsigned short* bn = stg3 + ((kt & 1) ^ 1) * 16384;
      if (kt < 3) {
#pragma unroll
        for (int j = 0; j < 2; ++j)
          ld_lds16(src3[j] + (kt + 1) * 64, bn + (wv * 2 + j) * 512, lane);
      }
#pragma unroll
      for (int ks = 0; ks < 2; ++ks) {
        const int ko = (ks * 32 + quad * 8) ^ swz;
        s8v af[4], bfv[2];
#pragma unroll
        for (int mt = 0; mt < 4; ++mt)
          af[mt] = *(const s8v*)(&xlstm[(size_t)(wm * 64 + mt * 16 + l15) * 260 + kt * 64 + ks * 32 + quad * 8]);
#pragma unroll
        for (int nt = 0; nt < 2; ++nt)
          bfv[nt] = *(const s8v*)(&bc[(wn * 32 + nt * 16 + l15) * 64 + ko]);
#pragma unroll
        for (int mt = 0; mt < 4; ++mt)
#pragma unroll
          for (int nt = 0; nt < 2; ++nt)
            acc3[mt][nt] = __builtin_amdgcn_mfma_f32_16x16x32_bf16(af[mt], bfv[nt], acc3[mt][nt], 0, 0, 0);
      }
      wait_vm0();
      __syncthreads();
    }
    // ---- EP3: +bias -> bf16 -> PRE (coalesced via sPb repack) -------------
    for (int ck = 0; ck < 4; ++ck) {
      const int lo = ck * 31;
#pragma unroll
      for (int mt = 0; mt < 4; ++mt) {
        int rbase = wm * 64 + mt * 16 + quad * 4 - lo;
#pragma unroll
        for (int nt = 0; nt < 2; ++nt) {
          int col = wn * 32 + nt * 16 + l15;
          float bias = sB3[p * 256 + col];
#pragma unroll
          for (int r = 0; r < 4; ++r) {
            int rr = rbase + r;
            if ((unsigned)rr < 31u) sPb[rr * 264 + col] = f2bf(acc3[mt][nt][r] + bias);
          }
        }
      }
      __syncthreads();
      if (tid < 992) {                           // 31 rows x 32 x 16B
        int row = tid >> 5, cq = (tid & 31) * 8;
        *(uint4*)(pre + (size_t)(rowBase + lo + row) * 512 + p * 256 + cq) =
            *(const uint4*)(&sPb[row * 264 + cq]);
      }
      __syncthreads();
    }
  }
}

// ===========================================================================
// k4: LSTM recurrence, one block = 16 batches x 1 direction; grid (256, 2)
// ===========================================================================
__global__ __launch_bounds__(256) void k4_lstm(
    const unsigned short* __restrict__ pre, const unsigned short* __restrict__ Whht,
    unsigned short* __restrict__ win) {
  __shared__ unsigned short sW[256 * 72];   // whh^T [n][k] padded
  __shared__ unsigned short sH[16 * 72];    // h bf16 [b][k] padded
  __shared__ float sG[16 * 260];            // gates fp32 [b][col]
  int tid = threadIdx.x;
  int dir = blockIdx.y;
  int b0  = blockIdx.x * 16;
  {                                         // stage whh^T for this dir
    const unsigned short* src = Whht + dir * 16384;
#pragma unroll
    for (int c = 0; c < 8; ++c) {
      int id = tid + c * 256;               // 2048 chunks of 8 bf16
      int row = id >> 3, kc = (id & 7) * 8;
      uint4 v = *(const uint4*)(src + row * 64 + kc);
      *(uint4*)(&sW[row * 72 + kc]) = v;
    }
  }
  for (int i = tid; i < 16 * 72; i += 256) sH[i] = 0;
  __syncthreads();

  const int lane = tid & 63, wv = tid >> 6, l15 = lane & 15, quad = lane >> 4;
  const int eb = tid >> 4, jb = (tid & 15) * 4;   // elementwise: batch, j-quad
  float cs[4] = {0.f, 0.f, 0.f, 0.f};

  // prefetch t=0's pre row
  int tt0 = dir ? 30 : 0;
  const unsigned short* pbase = pre + ((size_t)(b0 + eb) * 31) * 512 + dir * 256;
  ushort4 pi = *(const ushort4*)(pbase + tt0 * 512 + jb);
  ushort4 pf = *(const ushort4*)(pbase + tt0 * 512 + 64 + jb);
  ushort4 pg = *(const ushort4*)(pbase + tt0 * 512 + 128 + jb);
  ushort4 po = *(const ushort4*)(pbase + tt0 * 512 + 192 + jb);

  for (int t = 0; t < 31; ++t) {
    f4v acc[4];
#pragma unroll
    for (int nt = 0; nt < 4; ++nt) acc[nt] = (f4v){0.f, 0.f, 0.f, 0.f};
#pragma unroll
    for (int ks = 0; ks < 2; ++ks) {
      s8v af = *(const s8v*)(&sH[l15 * 72 + ks * 32 + quad * 8]);
#pragma unroll
      for (int nt = 0; nt < 4; ++nt) {
        int n = wv * 64 + nt * 16 + l15;
        s8v bfv = *(const s8v*)(&sW[n * 72 + ks * 32 + quad * 8]);
        acc[nt] = __builtin_amdgcn_mfma_f32_16x16x32_bf16(af, bfv, acc[nt], 0, 0, 0);
      }
    }
#pragma unroll
    for (int nt = 0; nt < 4; ++nt)
#pragma unroll
      for (int r = 0; r < 4; ++r)
        sG[(quad * 4 + r) * 260 + wv * 64 + nt * 16 + l15] = acc[nt][r];

    ushort4 ni, nf, ng, no;                 // prefetch t+1 before the barrier
    if (t < 30) {
      int ttn = dir ? 29 - t : t + 1;
      ni = *(const ushort4*)(pbase + ttn * 512 + jb);
      nf = *(const ushort4*)(pbase + ttn * 512 + 64 + jb);
      ng = *(const ushort4*)(pbase + ttn * 512 + 128 + jb);
      no = *(const ushort4*)(pbase + ttn * 512 + 192 + jb);
    }
    __syncthreads();

    int tt = dir ? 30 - t : t;
    const float* g = &sG[eb * 260];
    float hv[4];
#pragma unroll
    for (int jj = 0; jj < 4; ++jj) {
      int j = jb + jj;
      float vi = g[j]       + bf2f(jj == 0 ? pi.x : jj == 1 ? pi.y : jj == 2 ? pi.z : pi.w);
      float vf = g[64 + j]  + bf2f(jj == 0 ? pf.x : jj == 1 ? pf.y : jj == 2 ? pf.z : pf.w);
      float vg = g[128 + j] + bf2f(jj == 0 ? pg.x : jj == 1 ? pg.y : jj == 2 ? pg.z : pg.w);
      float vo = g[192 + j] + bf2f(jj == 0 ? po.x : jj == 1 ? po.y : jj == 2 ? po.z : po.w);
      float cc = fsig(vf) * cs[jj] + fsig(vi) * ftanh(vg);
      cs[jj] = cc;
      hv[jj] = fsig(vo) * ftanh(cc);
    }
    ushort4 hb;
    hb.x = f2bf(hv[0]); hb.y = f2bf(hv[1]); hb.z = f2bf(hv[2]); hb.w = f2bf(hv[3]);
    *(ushort4*)(&sH[eb * 72 + jb]) = hb;
    if (tt >= 10 && tt <= 20)
      *(ushort4*)(win + ((size_t)(b0 + eb) * 11 + (tt - 10)) * 128 + dir * 64 + jb) = hb;
    if (t < 30) { pi = ni; pf = nf; pg = ng; po = no; }
    __syncthreads();
  }
}

// ===========================================================================
// k5: attention over window + lin2 + gated blend with linear_logits -> d_out
// ===========================================================================
__global__ __launch_bounds__(256) void k5_attn(
    const unsigned short* __restrict__ win, const float* __restrict__ attn_w,
    const float* __restrict__ attn_b, const float* __restrict__ attn_t,
    const float* __restrict__ lin2_w, const float* __restrict__ lin2_b,
    const float* __restrict__ linlog, const float* __restrict__ gate,
    float* __restrict__ out) {
  __shared__ unsigned short sWin[176 * 128];
  __shared__ float sAw[128];
  __shared__ float sSc[176];
  __shared__ float sAtt[16 * 128];
  int tid = threadIdx.x;
  int b0  = blockIdx.x * 16;
#pragma unroll
  for (int c = 0; c < 11; ++c) {              // stage 16 batches x 11 t x 128 ch
    int id = tid + c * 256;
    int row = id >> 4, kc = (id & 15) * 8;
    uint4 v = *(const uint4*)(win + ((size_t)b0 * 11 + row) * 128 + kc);
    *(uint4*)(&sWin[row * 128 + kc]) = v;
  }
  if (tid < 128) sAw[tid] = attn_w[tid];
  __syncthreads();
  if (tid < 176) {                            // scores
    int b = tid / 11, wt = tid - b * 11;
    const unsigned short* w = &sWin[(b * 11 + wt) * 128];
    float dot = 0.f;
    for (int ch = 0; ch < 128; ++ch) dot += bf2f(w[ch]) * sAw[ch];
    float temp = logf(1.f + __expf(attn_t[0])) + 0.001f;
    sSc[tid] = (dot + attn_b[0]) / temp;
  }
  __syncthreads();
  if (tid < 16) {                             // softmax over 11
    float m = -1e30f;
    for (int wt = 0; wt < 11; ++wt) m = fmaxf(m, sSc[tid * 11 + wt]);
    float e[11], sum = 0.f;
    for (int wt = 0; wt < 11; ++wt) { e[wt] = __expf(sSc[tid * 11 + wt] - m); sum += e[wt]; }
    float inv = __fdividef(1.f, sum);
    for (int wt = 0; wt < 11; ++wt) sSc[tid * 11 + wt] = e[wt] * inv;
  }
  __syncthreads();
#pragma unroll
  for (int p = 0; p < 8; ++p) {               // attended (also an output)
    int task = tid + p * 256;
    int b = task >> 7, ch = task & 127;
    float a = 0.f;
    for (int wt = 0; wt < 11; ++wt)
      a += sSc[b * 11 + wt] * bf2f(sWin[(b * 11 + wt) * 128 + ch]);
    sAtt[b * 128 + ch] = a;
    out[49152 + (size_t)(b0 + b) * 128 + ch] = a;
  }
  __syncthreads();
  if (tid < 192) {                            // lstm_logits + gated blend
    int b = tid / 12, o = tid - b * 12;
    float dot = 0.f;
    for (int ch = 0; ch < 128; ++ch) dot += sAtt[b * 128 + ch] * lin2_w[ch * 12 + o];
    dot += lin2_b[o];
    float lin = linlog[(size_t)(b0 + b) * 12 + o];
    float gg = fsig(gate[0]);
    out[(size_t)(b0 + b) * 12 + o] = lin + gg * (dot - lin);
  }
}

// ===========================================================================
extern "C" void kernel_launch(void* const* d_in, const int* in_sizes, int n_in,
                              void* d_out, int out_size, void* d_ws, size_t ws_size,
                              hipStream_t stream) {
  const float* x       = (const float*)d_in[0];
  const float* cls_w   = (const float*)d_in[1];
  const float* cls_b   = (const float*)d_in[2];
  const float* delta_w = (const float*)d_in[3];
  const float* delta_b = (const float*)d_in[4];
  const float* acc_w   = (const float*)d_in[5];
  const float* acc_b   = (const float*)d_in[6];
  const float* cls_g   = (const float*)d_in[7];
  const float* cls_be  = (const float*)d_in[8];
  const float* del_g   = (const float*)d_in[9];
  const float* del_be  = (const float*)d_in[10];
  const float* accg    = (const float*)d_in[11];
  const float* accbe   = (const float*)d_in[12];
  const float* lin0_w  = (const float*)d_in[13];
  const float* lin0_b  = (const float*)d_in[14];
  const float* gate    = (const float*)d_in[15];
  const float* attn_w  = (const float*)d_in[16];
  const float* attn_b  = (const float*)d_in[17];
  const float* attn_t  = (const float*)d_in[18];
  const float* lin1_w  = (const float*)d_in[19];
  const float* lin1_b  = (const float*)d_in[20];
  const float* lin2_w  = (const float*)d_in[21];
  const float* lin2_b  = (const float*)d_in[22];
  const float* wih_f   = (const float*)d_in[23];
  const float* whh_f   = (const float*)d_in[24];
  const float* b_f     = (const float*)d_in[25];
  const float* wih_r   = (const float*)d_in[26];
  const float* whh_r   = (const float*)d_in[27];
  const float* b_r     = (const float*)d_in[28];

  char* ws = (char*)d_ws;
  unsigned short* W1t   = (unsigned short*)(ws + OFF_W1T);
  unsigned short* W2t   = (unsigned short*)(ws + OFF_W2T);
  unsigned short* Wiht  = (unsigned short*)(ws + OFF_WIHT);
  unsigned short* Whht  = (unsigned short*)(ws + OFF_WHHT);
  unsigned short* XS    = (unsigned short*)(ws + OFF_XS);
  unsigned short* PRE   = XS;  // x_smooth dead after k2; reuse region for pre
  float*          XW    = (float*)(ws + OFF_XW);
  float*          LL    = (float*)(ws + OFF_LL);
  unsigned short* WIN   = (unsigned short*)(ws + OFF_WIN);
  unsigned short* XAUG  = (unsigned short*)(ws + OFF_XAUG);
  float* out = (float*)d_out;

  k0_prep<<<2176, 256, 0, stream>>>(cls_w, delta_w, acc_w, lin0_w, wih_f, wih_r,
                                    whh_f, whh_r, (unsigned short*)ws);
  k1_ema<<<6144, 256, 0, stream>>>(x, XS, XW);
  k1b_linlog<<<4096, 64, 0, stream>>>(XW, lin1_w, lin1_b, LL);
  k2_aug<<<1024, 1024, 0, stream>>>(XS, W1t, cls_b, delta_b, acc_b,
                                    cls_g, cls_be, del_g, del_be, accg, accbe, XAUG);
  k3c_fused<<<1024, 1024, 0, stream>>>(XAUG, W2t, Wiht, lin0_b, b_f, b_r, PRE);
  k4_lstm<<<dim3(256, 2), 256, 0, stream>>>(PRE, Whht, WIN);
  k5_attn<<<256, 256, 0, stream>>>(WIN, attn_w, attn_b, attn_t, lin2_w, lin2_b,
                                   LL, gate, out);
}